// Round 2
// baseline (1326.802 us; speedup 1.0000x reference)
//
#include <hip/hip_runtime.h>
#include <math.h>

#define BB   4
#define SS   1024
#define HIDD 1024
#define NHH  16
#define HDD  64

// ---------------------------------------------------------------------------
// Generic NT GEMM: C[m,n] = sum_k A[m,k]*W[n,k]  (M=4096, N=1024, K=1024)
// mode 0: C[m*N+n] = acc + bias[n] + resid[m*N+n]      (output projection)
// mode 1: scatter to [b,h,s,d]: C[((b*NH+h)*S+s)*HD+d] = acc + bias[n]  (QKV)
// BM=128, BN=128, BK=16, 256 threads, 8x8 micro-tile on STRIDED rows/cols:
//   thread (ty,tx) owns rows {ty+16u}, cols {tx+16j}, u,j in [0,8).
// LDS row stride 20 floats: +16B-aligned for b128, and 20*t mod 32 distinct
// for t in [0,8) -> fragment reads conflict-free (A) / 2-way-free (W).
// ---------------------------------------------------------------------------
__global__ __launch_bounds__(256)
void gemm_nt(const float* __restrict__ A, const float* __restrict__ W,
             const float* __restrict__ bias, const float* __restrict__ resid,
             float* __restrict__ C, int mode)
{
    const int K = 1024, N = 1024;
    __shared__ float As[128][20];   // [row][k], stride 20
    __shared__ float Ws[128][20];   // [col][k]

    const int tid = threadIdx.x;
    const int ty = tid >> 4, tx = tid & 15;
    const int m0 = blockIdx.x * 128, n0 = blockIdx.y * 128;

    float acc[8][8];
#pragma unroll
    for (int u = 0; u < 8; ++u)
#pragma unroll
        for (int j = 0; j < 8; ++j) acc[u][j] = 0.f;

    const int srow = tid >> 2;      // 64 rows per 256-thread pass (2 passes)
    const int sc4  = tid & 3;       // which float4 of the 16-k row

    for (int k0 = 0; k0 < K; k0 += 16) {
        __syncthreads();
#pragma unroll
        for (int s = 0; s < 2; ++s) {
            int r = srow + 64 * s;
            float4 av = *(const float4*)&A[(size_t)(m0 + r) * K + k0 + 4 * sc4];
            *(float4*)&As[r][4 * sc4] = av;
            float4 wv = *(const float4*)&W[(size_t)(n0 + r) * K + k0 + 4 * sc4];
            *(float4*)&Ws[r][4 * sc4] = wv;
        }
        __syncthreads();

#pragma unroll
        for (int kq = 0; kq < 4; ++kq) {
            float4 a4[8], w4[8];
#pragma unroll
            for (int u = 0; u < 8; ++u)
                a4[u] = *(const float4*)&As[ty + 16 * u][4 * kq];
#pragma unroll
            for (int j = 0; j < 8; ++j)
                w4[j] = *(const float4*)&Ws[tx + 16 * j][4 * kq];
#pragma unroll
            for (int u = 0; u < 8; ++u)
#pragma unroll
                for (int j = 0; j < 8; ++j) {
                    acc[u][j] = fmaf(a4[u].x, w4[j].x, acc[u][j]);
                    acc[u][j] = fmaf(a4[u].y, w4[j].y, acc[u][j]);
                    acc[u][j] = fmaf(a4[u].z, w4[j].z, acc[u][j]);
                    acc[u][j] = fmaf(a4[u].w, w4[j].w, acc[u][j]);
                }
        }
    }

    if (mode == 0) {
#pragma unroll
        for (int u = 0; u < 8; ++u) {
            int m = m0 + ty + 16 * u;
#pragma unroll
            for (int j = 0; j < 8; ++j) {
                int n = n0 + tx + 16 * j;
                C[(size_t)m * N + n] = acc[u][j] + bias[n] + resid[(size_t)m * N + n];
            }
        }
    } else {
#pragma unroll
        for (int u = 0; u < 8; ++u) {
            int m = m0 + ty + 16 * u;
            int b = m >> 10, s = m & 1023;
#pragma unroll
            for (int j = 0; j < 8; ++j) {
                int n = n0 + tx + 16 * j;
                int h = n >> 6, d = n & 63;
                C[((size_t)(b * NHH + h) * SS + s) * HDD + d] = acc[u][j] + bias[n];
            }
        }
    }
}

// ---------------------------------------------------------------------------
// Transpose K: [bh][s][d] -> [bh][d][s] so attention K staging is coalesced
// (global) and conflict-free (LDS). grid (S/64, B*NH), 256 threads.
// ---------------------------------------------------------------------------
__global__ __launch_bounds__(256)
void ktrans(const float* __restrict__ kin, float* __restrict__ kout)
{
    __shared__ float t[64][65];
    const int tid = threadIdx.x;
    const int r0 = blockIdx.x * 64;
    const int bh = blockIdx.y;
    const float* src = kin + (size_t)bh * SS * HDD;
    float* dst = kout + (size_t)bh * SS * HDD;
#pragma unroll
    for (int s = 0; s < 4; ++s) {
        int idx = tid + 256 * s;
        int r = idx >> 4, c4 = idx & 15;
        float4 kv = *(const float4*)&src[(size_t)(r0 + r) * HDD + 4 * c4];
        t[r][4*c4+0] = kv.x; t[r][4*c4+1] = kv.y;
        t[r][4*c4+2] = kv.z; t[r][4*c4+3] = kv.w;
    }
    __syncthreads();
#pragma unroll
    for (int s = 0; s < 4; ++s) {
        int idx = tid + 256 * s;
        int d = idx >> 4, r4 = idx & 15;
        float4 o;
        o.x = t[4*r4+0][d]; o.y = t[4*r4+1][d];
        o.z = t[4*r4+2][d]; o.w = t[4*r4+3][d];
        *(float4*)&dst[(size_t)d * SS + r0 + 4*r4] = o;
    }
}

// ---------------------------------------------------------------------------
// Flash-style attention with relative_key_query bias.
// grid (S/32, B*NH), 256 threads. LTILE=32 q-rows, RT=64 r-cols per tile.
// Thread (ty,tx): ty in [0,16) owns rows 2ty..2ty+1, tx in [0,16) owns 4 cols.
// score = ( q.k + (q+k).pe[l-r] ) * 0.125 + mask[b][r]
// Online softmax state (m,l) lives in registers, replicated across the 16
// lanes of each row group (reduces via shfl_xor stay inside 16-lane groups).
// ---------------------------------------------------------------------------
__global__ __launch_bounds__(256, 2)
void attn(const float* __restrict__ q, const float* __restrict__ kt,
          const float* __restrict__ v, const float* __restrict__ mask,
          const float* __restrict__ de, float* __restrict__ ctx)
{
    __shared__ float q_t[64][32];    // [d][al]
    __shared__ float k_t[64][64];    // [d][ar]
    __shared__ float pe_t[64][96];   // [d][tloc], tloc = al-ar+63 in [0,94]
    __shared__ float v_s[64][64];    // [ar][d]
    __shared__ float p_t[64][36];    // [ar][row]
    __shared__ float mask_s[64];

    const int tid = threadIdx.x;
    const int ty = tid >> 4, tx = tid & 15;
    const int l0 = blockIdx.x * 32;
    const int bh = blockIdx.y;
    const int b = bh >> 4, h = bh & 15;

    const float* qb  = q  + (size_t)bh * SS * HDD;
    const float* ktb = kt + (size_t)bh * SS * HDD;  // [d][s]
    const float* vb  = v  + (size_t)bh * SS * HDD;

    // stage Q transposed (once per block)
#pragma unroll
    for (int s = 0; s < 2; ++s) {
        int idx = tid + 256 * s;          // [0,512)
        int al = idx & 31, c4 = idx >> 5;
        float4 qv = *(const float4*)&qb[(size_t)(l0 + al) * HDD + 4 * c4];
        q_t[4*c4+0][al] = qv.x; q_t[4*c4+1][al] = qv.y;
        q_t[4*c4+2][al] = qv.z; q_t[4*c4+3][al] = qv.w;
    }

    float o[2][4];
#pragma unroll
    for (int i = 0; i < 2; ++i)
#pragma unroll
        for (int j = 0; j < 4; ++j) o[i][j] = 0.f;
    float m_run[2] = {-1e30f, -1e30f};
    float l_run[2] = {0.f, 0.f};

    const int pbase = 2*ty - 4*tx + 60;   // in [0,90]

    for (int rt = 0; rt < 16; ++rt) {
        const int r0 = rt * 64;
        __syncthreads();
        // K tile from transposed global: coalesced read, conflict-free write
#pragma unroll
        for (int s = 0; s < 4; ++s) {
            int idx = tid + 256 * s;
            int d = idx >> 4, r4 = idx & 15;
            float4 kv = *(const float4*)&ktb[(size_t)d * SS + r0 + 4*r4];
            *(float4*)&k_t[d][4*r4] = kv;
        }
        // V tile natural layout
#pragma unroll
        for (int s = 0; s < 4; ++s) {
            int idx = tid + 256 * s;
            int ar = idx >> 4, c4 = idx & 15;
            float4 vv = *(const float4*)&vb[(size_t)(r0 + ar) * HDD + 4*c4];
            *(float4*)&v_s[ar][4*c4] = vv;
        }
        // PE band tile (transposed): rows tloc in [0,96); row 95 is never read
        {
            int g0 = l0 - r0 + 960;
#pragma unroll
            for (int s = 0; s < 6; ++s) {
                int idx = tid + 256 * s;   // [0,1536)
                int c4 = idx / 96;
                int tl = idx - c4 * 96;
                int gt = g0 + tl; if (gt > 2046) gt = 2046;
                float4 pv4 = *(const float4*)&de[(size_t)gt * HDD + 4 * c4];
                pe_t[4*c4+0][tl] = pv4.x; pe_t[4*c4+1][tl] = pv4.y;
                pe_t[4*c4+2][tl] = pv4.z; pe_t[4*c4+3][tl] = pv4.w;
            }
        }
        if (tid < 64) mask_s[tid] = mask[b * SS + r0 + tid];
        __syncthreads();

        // ----- scores -----
        float aqk[2][4], ape[2][4];
#pragma unroll
        for (int i = 0; i < 2; ++i)
#pragma unroll
            for (int j = 0; j < 4; ++j) { aqk[i][j] = 0.f; ape[i][j] = 0.f; }

#pragma unroll 8
        for (int d = 0; d < 64; ++d) {
            float2 qv = *(const float2*)&q_t[d][2*ty];
            float4 kv = *(const float4*)&k_t[d][4*tx];
            float2 pa = *(const float2*)&pe_t[d][pbase];
            float2 pb = *(const float2*)&pe_t[d][pbase+2];
            float  pc = pe_t[d][pbase+4];
            float pvv[5] = {pa.x, pa.y, pb.x, pb.y, pc};
            float qq[2] = {qv.x, qv.y};
            float kk[4] = {kv.x, kv.y, kv.z, kv.w};
#pragma unroll
            for (int i = 0; i < 2; ++i)
#pragma unroll
                for (int j = 0; j < 4; ++j) {
                    aqk[i][j] = fmaf(qq[i], kk[j], aqk[i][j]);
                    ape[i][j] = fmaf(qq[i] + kk[j], pvv[3 + i - j], ape[i][j]);
                }
        }

        // ----- online softmax update -----
        float pr[2][4], fsc[2];
#pragma unroll
        for (int i = 0; i < 2; ++i) {
            float sc[4];
#pragma unroll
            for (int j = 0; j < 4; ++j)
                sc[j] = (aqk[i][j] + ape[i][j]) * 0.125f + mask_s[4*tx + j];
            float rm = fmaxf(fmaxf(sc[0], sc[1]), fmaxf(sc[2], sc[3]));
            rm = fmaxf(rm, __shfl_xor(rm, 1));
            rm = fmaxf(rm, __shfl_xor(rm, 2));
            rm = fmaxf(rm, __shfl_xor(rm, 4));
            rm = fmaxf(rm, __shfl_xor(rm, 8));
            float mn = fmaxf(m_run[i], rm);
            float rs = 0.f;
#pragma unroll
            for (int j = 0; j < 4; ++j) { pr[i][j] = __expf(sc[j] - mn); rs += pr[i][j]; }
            rs += __shfl_xor(rs, 1);
            rs += __shfl_xor(rs, 2);
            rs += __shfl_xor(rs, 4);
            rs += __shfl_xor(rs, 8);
            float f = __expf(m_run[i] - mn);
            l_run[i] = l_run[i] * f + rs;
            m_run[i] = mn;
            fsc[i] = f;
        }
#pragma unroll
        for (int j = 0; j < 4; ++j) {
            float2 w2; w2.x = pr[0][j]; w2.y = pr[1][j];
            *(float2*)&p_t[4*tx + j][2*ty] = w2;
        }
#pragma unroll
        for (int i = 0; i < 2; ++i)
#pragma unroll
            for (int j = 0; j < 4; ++j) o[i][j] *= fsc[i];
        __syncthreads();

        // ----- PV accumulate -----
#pragma unroll 8
        for (int ar = 0; ar < 64; ++ar) {
            float2 pp = *(const float2*)&p_t[ar][2*ty];
            float4 vv = *(const float4*)&v_s[ar][4*tx];
            float p2[2] = {pp.x, pp.y};
            float v4[4] = {vv.x, vv.y, vv.z, vv.w};
#pragma unroll
            for (int i = 0; i < 2; ++i)
#pragma unroll
                for (int j = 0; j < 4; ++j)
                    o[i][j] = fmaf(p2[i], v4[j], o[i][j]);
        }
    }

    // write ctx in [b][s][h*64+d] layout
#pragma unroll
    for (int i = 0; i < 2; ++i) {
        float inv = 1.f / l_run[i];
        int srow = l0 + 2*ty + i;
        float4 ov;
        ov.x = o[i][0]*inv; ov.y = o[i][1]*inv;
        ov.z = o[i][2]*inv; ov.w = o[i][3]*inv;
        *(float4*)&ctx[((size_t)(b * SS + srow) * HIDD) + h * HDD + 4*tx] = ov;
    }
}

// ---------------------------------------------------------------------------
// Row LayerNorm over 1024 (input already has bias+residual folded in).
// ---------------------------------------------------------------------------
__global__ __launch_bounds__(256)
void ln_out(const float* __restrict__ hin, const float* __restrict__ g,
            const float* __restrict__ be, float* __restrict__ out)
{
    __shared__ float ssum[4], ssq[4];
    const int row = blockIdx.x;
    const int tid = threadIdx.x;
    float4 x = *(const float4*)&hin[(size_t)row * HIDD + 4 * tid];
    float sum = x.x + x.y + x.z + x.w;
    float sq  = x.x*x.x + x.y*x.y + x.z*x.z + x.w*x.w;
#pragma unroll
    for (int msk = 1; msk < 64; msk <<= 1) {
        sum += __shfl_xor(sum, msk);
        sq  += __shfl_xor(sq,  msk);
    }
    if ((tid & 63) == 0) { ssum[tid >> 6] = sum; ssq[tid >> 6] = sq; }
    __syncthreads();
    sum = ssum[0] + ssum[1] + ssum[2] + ssum[3];
    sq  = ssq[0]  + ssq[1]  + ssq[2]  + ssq[3];
    float mu  = sum * (1.f / 1024.f);
    float var = sq * (1.f / 1024.f) - mu * mu;
    float inv = rsqrtf(var + 1e-12f);
    float4 gv = *(const float4*)&g[4*tid];
    float4 bvv = *(const float4*)&be[4*tid];
    float4 o;
    o.x = (x.x - mu) * inv * gv.x + bvv.x;
    o.y = (x.y - mu) * inv * gv.y + bvv.y;
    o.z = (x.z - mu) * inv * gv.z + bvv.z;
    o.w = (x.w - mu) * inv * gv.w + bvv.w;
    *(float4*)&out[(size_t)row * HIDD + 4 * tid] = o;
}

// ---------------------------------------------------------------------------
extern "C" void kernel_launch(void* const* d_in, const int* in_sizes, int n_in,
                              void* d_out, int out_size, void* d_ws, size_t ws_size,
                              hipStream_t stream)
{
    const float* hid  = (const float*)d_in[0];
    const float* mask = (const float*)d_in[1];
    const float* Wq   = (const float*)d_in[2];
    const float* bq   = (const float*)d_in[3];
    const float* Wk   = (const float*)d_in[4];
    const float* bk   = (const float*)d_in[5];
    const float* Wv   = (const float*)d_in[6];
    const float* bv   = (const float*)d_in[7];
    const float* de   = (const float*)d_in[8];
    const float* Wo   = (const float*)d_in[9];
    const float* bo   = (const float*)d_in[10];
    const float* lng  = (const float*)d_in[11];
    const float* lnb  = (const float*)d_in[12];
    float* out = (float*)d_out;

    const size_t MAT = (size_t)BB * SS * HIDD;  // 4M floats
    float* ws     = (float*)d_ws;
    float* q_ws   = ws;              // [bh][s][d]
    float* k_ws   = ws + MAT;        // [bh][s][d]
    float* v_ws   = ws + 2*MAT;      // [bh][s][d]
    float* kt_ws  = ws + 3*MAT;      // [bh][d][s]
    float* ctx_ws = k_ws;            // reuse: k_ws dead after ktrans
    float* h_ws   = q_ws;            // reuse: q_ws dead after attn

    dim3 gg(32, 8);  // M/128 x N/128
    gemm_nt<<<gg, 256, 0, stream>>>(hid, Wq, bq, nullptr, q_ws, 1);
    gemm_nt<<<gg, 256, 0, stream>>>(hid, Wk, bk, nullptr, k_ws, 1);
    gemm_nt<<<gg, 256, 0, stream>>>(hid, Wv, bv, nullptr, v_ws, 1);
    ktrans<<<dim3(16, 64), 256, 0, stream>>>(k_ws, kt_ws);
    attn<<<dim3(32, 64), 256, 0, stream>>>(q_ws, kt_ws, v_ws, mask, de, ctx_ws);
    gemm_nt<<<gg, 256, 0, stream>>>(ctx_ws, Wo, bo, hid, h_ws, 0);
    ln_out<<<4096, 256, 0, stream>>>(h_ws, lng, lnb, out);
}

// Round 4
// 318.308 us; speedup vs baseline: 4.1683x; 4.1683x over previous
//
#include <hip/hip_runtime.h>
#include <math.h>

#define BB   4
#define SS   1024
#define HIDD 1024
#define NHH  16
#define HDD  64

typedef short  short8 __attribute__((ext_vector_type(8)));
typedef float  f32x4  __attribute__((ext_vector_type(4)));

__device__ inline unsigned short f2bf(float f) {
    unsigned int u = __float_as_uint(f);
    u = (u + 0x7FFFu + ((u >> 16) & 1u)) >> 16;
    return (unsigned short)u;
}
__device__ inline float bf2f(unsigned short h) {
    return __uint_as_float(((unsigned int)h) << 16);
}

// ---------------------------------------------------------------------------
// fp32 -> bf16 conversion kernels
// ---------------------------------------------------------------------------
__global__ __launch_bounds__(256)
void conv_f2b(const float* __restrict__ s, unsigned short* __restrict__ d, int n)
{
    int i = (blockIdx.x * 256 + threadIdx.x) * 8;
    if (i >= n) return;
    float4 a = *(const float4*)&s[i];
    float4 b = *(const float4*)&s[i + 4];
    short8 o;
    o[0]=f2bf(a.x); o[1]=f2bf(a.y); o[2]=f2bf(a.z); o[3]=f2bf(a.w);
    o[4]=f2bf(b.x); o[5]=f2bf(b.y); o[6]=f2bf(b.z); o[7]=f2bf(b.w);
    *(short8*)&d[i] = o;
}

// Wq|Wk|Wv|Wo (each 1M fp32) -> contiguous 4M bf16
__global__ __launch_bounds__(256)
void conv_w(const float* __restrict__ wq, const float* __restrict__ wk,
            const float* __restrict__ wv, const float* __restrict__ wo,
            unsigned short* __restrict__ d)
{
    int i = (blockIdx.x * 256 + threadIdx.x) * 8;
    const float* s; int off;
    if      (i < 1048576)  { s = wq; off = i; }
    else if (i < 2097152)  { s = wk; off = i - 1048576; }
    else if (i < 3145728)  { s = wv; off = i - 2097152; }
    else                   { s = wo; off = i - 3145728; }
    float4 a = *(const float4*)&s[off];
    float4 b = *(const float4*)&s[off + 4];
    short8 o;
    o[0]=f2bf(a.x); o[1]=f2bf(a.y); o[2]=f2bf(a.z); o[3]=f2bf(a.w);
    o[4]=f2bf(b.x); o[5]=f2bf(b.y); o[6]=f2bf(b.z); o[7]=f2bf(b.w);
    *(short8*)&d[i] = o;
}

// dist_emb 2047*64 fp32 -> bf16, zero-padded to 2048 rows
__global__ __launch_bounds__(256)
void conv_de(const float* __restrict__ s, unsigned short* __restrict__ d)
{
    int i = (blockIdx.x * 256 + threadIdx.x) * 8;   // grid 64 -> covers 131072
    short8 o;
    if (i < 131008) {
        float4 a = *(const float4*)&s[i];
        float4 b = *(const float4*)&s[i + 4];
        o[0]=f2bf(a.x); o[1]=f2bf(a.y); o[2]=f2bf(a.z); o[3]=f2bf(a.w);
        o[4]=f2bf(b.x); o[5]=f2bf(b.y); o[6]=f2bf(b.z); o[7]=f2bf(b.w);
    } else {
        o = (short8)0;
    }
    *(short8*)&d[i] = o;
}

// ---------------------------------------------------------------------------
// bf16 MFMA NT GEMM: C[m,n] = sum_k A[m,k]*W[n,k], M=4096, K=1024.
// mode 1 (QKV): grid.y=24, sel=nb/8 picks Wq/Wk/Wv slice and q/k/v output,
//   writes bf16 [bh][s][d] with bias.
// mode 0 (out-proj): grid.y=8, writes fp32 C[m][n] = acc + bias + resid.
// 128x128 tile, BK=32, 4 waves (each 64x64 = 4x4 frags of 16x16x32).
// ---------------------------------------------------------------------------
__global__ __launch_bounds__(256)
void gemm_bf16(const unsigned short* __restrict__ A,
               const unsigned short* __restrict__ W,
               const float* __restrict__ bias0, const float* __restrict__ bias1,
               const float* __restrict__ bias2, const float* __restrict__ resid,
               unsigned short* __restrict__ oq, unsigned short* __restrict__ ok,
               unsigned short* __restrict__ ov, float* __restrict__ oc, int mode)
{
    __shared__ unsigned short A_l[128][40];
    __shared__ unsigned short B_l[128][40];

    const int tid = threadIdx.x;
    const int lane = tid & 63, w = tid >> 6;
    const int g = lane >> 4, x = lane & 15;
    const int m0 = blockIdx.x * 128;

    int sel = 0, n0;
    const unsigned short* Wp;
    if (mode == 1) { sel = blockIdx.y >> 3; n0 = (blockIdx.y & 7) * 128;
                     Wp = W + (size_t)sel * 1048576; }
    else           { n0 = blockIdx.y * 128; Wp = W; }

    f32x4 acc[4][4];
#pragma unroll
    for (int i = 0; i < 4; ++i)
#pragma unroll
        for (int j = 0; j < 4; ++j) acc[i][j] = (f32x4){0.f, 0.f, 0.f, 0.f};

    const int srow = tid >> 2, sc8 = (tid & 3) * 8;
    const unsigned short* Ap = A  + (size_t)(m0 + srow) * 1024 + sc8;
    const unsigned short* Bp = Wp + (size_t)(n0 + srow) * 1024 + sc8;

    short8 ra0 = *(const short8*)(Ap);
    short8 ra1 = *(const short8*)(Ap + 64 * 1024);
    short8 rb0 = *(const short8*)(Bp);
    short8 rb1 = *(const short8*)(Bp + 64 * 1024);

    const int mo = (w >> 1) * 64, no = (w & 1) * 64;
    const int fcol = g * 8;

    for (int ks = 0; ks < 32; ++ks) {
        __syncthreads();
        *(short8*)&A_l[srow     ][sc8] = ra0;
        *(short8*)&A_l[srow + 64][sc8] = ra1;
        *(short8*)&B_l[srow     ][sc8] = rb0;
        *(short8*)&B_l[srow + 64][sc8] = rb1;
        __syncthreads();
        if (ks < 31) {
            int k0 = (ks + 1) * 32;
            ra0 = *(const short8*)(Ap + k0);
            ra1 = *(const short8*)(Ap + 64 * 1024 + k0);
            rb0 = *(const short8*)(Bp + k0);
            rb1 = *(const short8*)(Bp + 64 * 1024 + k0);
        }
        short8 af[4], bf[4];
#pragma unroll
        for (int mi = 0; mi < 4; ++mi)
            af[mi] = *(const short8*)&A_l[mo + 16 * mi + x][fcol];
#pragma unroll
        for (int ni = 0; ni < 4; ++ni)
            bf[ni] = *(const short8*)&B_l[no + 16 * ni + x][fcol];
#pragma unroll
        for (int mi = 0; mi < 4; ++mi)
#pragma unroll
            for (int ni = 0; ni < 4; ++ni)
                acc[mi][ni] = __builtin_amdgcn_mfma_f32_16x16x32_bf16(
                    af[mi], bf[ni], acc[mi][ni], 0, 0, 0);
    }

    if (mode == 0) {
#pragma unroll
        for (int mi = 0; mi < 4; ++mi)
#pragma unroll
            for (int reg = 0; reg < 4; ++reg) {
                int m = m0 + mo + 16 * mi + g * 4 + reg;
#pragma unroll
                for (int ni = 0; ni < 4; ++ni) {
                    int n = n0 + no + 16 * ni + x;
                    oc[(size_t)m * 1024 + n] =
                        acc[mi][ni][reg] + bias0[n] + resid[(size_t)m * 1024 + n];
                }
            }
    } else {
        const float* bias = (sel == 0) ? bias0 : (sel == 1) ? bias1 : bias2;
        unsigned short* op = (sel == 0) ? oq : (sel == 1) ? ok : ov;
#pragma unroll
        for (int mi = 0; mi < 4; ++mi)
#pragma unroll
            for (int reg = 0; reg < 4; ++reg) {
                int m = m0 + mo + 16 * mi + g * 4 + reg;
                int b = m >> 10, s = m & 1023;
#pragma unroll
                for (int ni = 0; ni < 4; ++ni) {
                    int n = n0 + no + 16 * ni + x;
                    int h = n >> 6, d = n & 63;
                    op[((size_t)(b * NHH + h) * SS + s) * HDD + d] =
                        f2bf(acc[mi][ni][reg] + bias[n]);
                }
            }
    }
}

// ---------------------------------------------------------------------------
// bf16 transpose: v[bh][s][d] -> vt[bh][d][s]
// ---------------------------------------------------------------------------
__global__ __launch_bounds__(256)
void vtrans(const unsigned short* __restrict__ vi, unsigned short* __restrict__ vo)
{
    __shared__ unsigned short t[64][72];
    const int tid = threadIdx.x;
    const int s0 = blockIdx.x * 64, bh = blockIdx.y;
    const unsigned short* src = vi + (size_t)bh * SS * HDD;
    unsigned short* dst = vo + (size_t)bh * SS * HDD;
#pragma unroll
    for (int c = 0; c < 2; ++c) {
        int idx = tid + 256 * c, row = idx >> 3, c8 = (idx & 7) * 8;
        *(short8*)&t[row][c8] = *(const short8*)&src[(size_t)(s0 + row) * 64 + c8];
    }
    __syncthreads();
#pragma unroll
    for (int c = 0; c < 2; ++c) {
        int idx = tid + 256 * c, d = idx >> 3, s8 = (idx & 7) * 8;
        short8 o;
#pragma unroll
        for (int j = 0; j < 8; ++j) o[j] = t[s8 + j][d];
        *(short8*)&dst[(size_t)d * 1024 + s0 + s8] = o;
    }
}

// ---------------------------------------------------------------------------
// MFMA flash attention with relative_key_query bias.
// grid (S/64, B*NH), 256 threads (4 waves). Per r-tile (64):
//   S'[r,l] = K·Q^T (transposed scores: softmax reduce is in-register)
//   QPE[t,l] = PE_band·Q^T, KPE[t,r] = PE_band·K^T (PE A-frags from global)
//   score(l,r) = (S' + QPE[l-r+63,l] + KPE[l-r+63,r])*0.125 + mask[r]
//   online softmax -> P bf16 -> LDS -> PV MFMA (ctx += P·V)
// Wave w owns score columns l' in [16w,16w+16) and ctx rows same.
// ---------------------------------------------------------------------------
__global__ __launch_bounds__(256, 2)
void attn_mfma(const unsigned short* __restrict__ qg,
               const unsigned short* __restrict__ kg,
               const unsigned short* __restrict__ vtg,
               const float* __restrict__ mask,
               const unsigned short* __restrict__ de,
               unsigned short* __restrict__ ctx)
{
    __shared__ unsigned short Q_s [64][72];
    __shared__ unsigned short K_s [64][72];
    __shared__ unsigned short Vt_s[64][72];
    __shared__ unsigned short QPE_s[128][66];
    __shared__ unsigned short KPE_s[128][66];
    __shared__ unsigned short P_s [64][72];
    __shared__ float mask_s[64];

    const int tid = threadIdx.x;
    const int w = tid >> 6, lane = tid & 63;
    const int g = lane >> 4, x = lane & 15;
    const int l0 = blockIdx.x * 64, bh = blockIdx.y;
    const int b = bh >> 4, h = bh & 15;

    const unsigned short* qb = qg  + (size_t)bh * SS * HDD;   // [l][d]
    const unsigned short* kb = kg  + (size_t)bh * SS * HDD;   // [r][d]
    const unsigned short* vb = vtg + (size_t)bh * SS * HDD;   // [d][s]

#pragma unroll
    for (int c = 0; c < 2; ++c) {
        int idx = tid + 256 * c, row = idx >> 3, c8 = (idx & 7) * 8;
        *(short8*)&Q_s[row][c8] = *(const short8*)&qb[(size_t)(l0 + row) * 64 + c8];
    }
    __syncthreads();

    short8 qf[4][2];
#pragma unroll
    for (int lf = 0; lf < 4; ++lf)
#pragma unroll
        for (int ks = 0; ks < 2; ++ks)
            qf[lf][ks] = *(const short8*)&Q_s[16 * lf + x][g * 8 + 32 * ks];

    f32x4 cacc[4];
#pragma unroll
    for (int i = 0; i < 4; ++i) cacc[i] = (f32x4){0.f, 0.f, 0.f, 0.f};
    float m_run = -1e30f, l_run = 0.f;
    const int lcol = 16 * w + x;

    for (int rt = 0; rt < 16; ++rt) {
        const int r0 = rt * 64;
        __syncthreads();   // A: prev-tile LDS reads complete
#pragma unroll
        for (int c = 0; c < 2; ++c) {
            int idx = tid + 256 * c, row = idx >> 3, c8 = (idx & 7) * 8;
            *(short8*)&K_s [row][c8] = *(const short8*)&kb[(size_t)(r0 + row) * 64 + c8];
            *(short8*)&Vt_s[row][c8] = *(const short8*)&vb[(size_t)row * 1024 + r0 + c8];
        }
        if (tid < 16) *(float4*)&mask_s[tid * 4] =
            *(const float4*)&mask[b * SS + r0 + tid * 4];
        __syncthreads();   // B: tiles staged

        short8 kf[4][2];
#pragma unroll
        for (int rf = 0; rf < 4; ++rf)
#pragma unroll
            for (int ks = 0; ks < 2; ++ks)
                kf[rf][ks] = *(const short8*)&K_s[16 * rf + x][g * 8 + 32 * ks];

        // S' = K·Q^T (this wave's 16 l-columns)
        f32x4 sacc[4];
#pragma unroll
        for (int i = 0; i < 4; ++i) sacc[i] = (f32x4){0.f, 0.f, 0.f, 0.f};
#pragma unroll
        for (int rf = 0; rf < 4; ++rf)
#pragma unroll
            for (int ks = 0; ks < 2; ++ks)
                sacc[rf] = __builtin_amdgcn_mfma_f32_16x16x32_bf16(
                    kf[rf][ks], qf[w][ks], sacc[rf], 0, 0, 0);

        // QPE / KPE (wave w owns t-rows [32w, 32w+32))
        const int t0 = l0 - r0 + 960;
        f32x4 qpe[2][4], kpe[2][4];
#pragma unroll
        for (int i = 0; i < 2; ++i)
#pragma unroll
            for (int j = 0; j < 4; ++j) {
                qpe[i][j] = (f32x4){0.f, 0.f, 0.f, 0.f};
                kpe[i][j] = (f32x4){0.f, 0.f, 0.f, 0.f};
            }
#pragma unroll
        for (int tf = 0; tf < 2; ++tf)
#pragma unroll
            for (int ks = 0; ks < 2; ++ks) {
                short8 pf = *(const short8*)&de[
                    (size_t)(t0 + 32 * w + 16 * tf + x) * 64 + g * 8 + 32 * ks];
#pragma unroll
                for (int lf = 0; lf < 4; ++lf)
                    qpe[tf][lf] = __builtin_amdgcn_mfma_f32_16x16x32_bf16(
                        pf, qf[lf][ks], qpe[tf][lf], 0, 0, 0);
#pragma unroll
                for (int rf = 0; rf < 4; ++rf)
                    kpe[tf][rf] = __builtin_amdgcn_mfma_f32_16x16x32_bf16(
                        pf, kf[rf][ks], kpe[tf][rf], 0, 0, 0);
            }
#pragma unroll
        for (int tf = 0; tf < 2; ++tf)
#pragma unroll
            for (int j = 0; j < 4; ++j)
#pragma unroll
                for (int reg = 0; reg < 4; ++reg) {
                    int t = 32 * w + 16 * tf + g * 4 + reg;
                    QPE_s[t][16 * j + x] = f2bf(qpe[tf][j][reg]);
                    KPE_s[t][16 * j + x] = f2bf(kpe[tf][j][reg]);
                }
        __syncthreads();   // C: QPE/KPE visible

        // assemble scores + online softmax (lane owns col lcol, 16 r's)
        float sc[4][4];
        float rmax = -1e30f;
#pragma unroll
        for (int fr = 0; fr < 4; ++fr)
#pragma unroll
            for (int reg = 0; reg < 4; ++reg) {
                int rr = 16 * fr + g * 4 + reg;
                int tl = lcol - rr + 63;
                float v = (sacc[fr][reg] + bf2f(QPE_s[tl][lcol])
                           + bf2f(KPE_s[tl][rr])) * 0.125f + mask_s[rr];
                sc[fr][reg] = v;
                rmax = fmaxf(rmax, v);
            }
        rmax = fmaxf(rmax, __shfl_xor(rmax, 16));
        rmax = fmaxf(rmax, __shfl_xor(rmax, 32));
        float mn = fmaxf(m_run, rmax);
        float rs = 0.f;
        float pr[4][4];
#pragma unroll
        for (int fr = 0; fr < 4; ++fr)
#pragma unroll
            for (int reg = 0; reg < 4; ++reg) {
                float p = __expf(sc[fr][reg] - mn);
                pr[fr][reg] = p; rs += p;
            }
        rs += __shfl_xor(rs, 16);
        rs += __shfl_xor(rs, 32);
        float fsc = __expf(m_run - mn);
        l_run = l_run * fsc + rs;
        m_run = mn;
#pragma unroll
        for (int fr = 0; fr < 4; ++fr) {
            uint2 pu;
            pu.x = (unsigned int)f2bf(pr[fr][0]) | ((unsigned int)f2bf(pr[fr][1]) << 16);
            pu.y = (unsigned int)f2bf(pr[fr][2]) | ((unsigned int)f2bf(pr[fr][3]) << 16);
            *(uint2*)&P_s[lcol][16 * fr + 4 * g] = pu;
        }
        __syncthreads();   // D: P visible

        // rescale ctx + PV
        float fr4[4];
#pragma unroll
        for (int reg = 0; reg < 4; ++reg)
            fr4[reg] = __shfl(fsc, (g << 4) + (g << 2) + reg);
#pragma unroll
        for (int df = 0; df < 4; ++df)
#pragma unroll
            for (int reg = 0; reg < 4; ++reg)
                cacc[df][reg] *= fr4[reg];

        short8 pa[2];
#pragma unroll
        for (int ks = 0; ks < 2; ++ks)
            pa[ks] = *(const short8*)&P_s[16 * w + x][g * 8 + 32 * ks];
#pragma unroll
        for (int df = 0; df < 4; ++df)
#pragma unroll
            for (int ks = 0; ks < 2; ++ks) {
                short8 vf = *(const short8*)&Vt_s[16 * df + x][g * 8 + 32 * ks];
                cacc[df] = __builtin_amdgcn_mfma_f32_16x16x32_bf16(
                    pa[ks], vf, cacc[df], 0, 0, 0);
            }
    }

    float inv4[4];
#pragma unroll
    for (int reg = 0; reg < 4; ++reg)
        inv4[reg] = 1.f / __shfl(l_run, (g << 4) + (g << 2) + reg);
#pragma unroll
    for (int df = 0; df < 4; ++df)
#pragma unroll
        for (int reg = 0; reg < 4; ++reg) {
            int s = l0 + 16 * w + 4 * g + reg;
            int d = 16 * df + x;
            ctx[((size_t)(b * SS + s) * HIDD) + h * HDD + d] =
                f2bf(cacc[df][reg] * inv4[reg]);
        }
}

// ---------------------------------------------------------------------------
// Row LayerNorm over 1024 (input has bias+residual folded in).
// ---------------------------------------------------------------------------
__global__ __launch_bounds__(256)
void ln_out(const float* __restrict__ hin, const float* __restrict__ g,
            const float* __restrict__ be, float* __restrict__ out)
{
    __shared__ float ssum[4], ssq[4];
    const int row = blockIdx.x;
    const int tid = threadIdx.x;
    float4 x = *(const float4*)&hin[(size_t)row * HIDD + 4 * tid];
    float sum = x.x + x.y + x.z + x.w;
    float sq  = x.x*x.x + x.y*x.y + x.z*x.z + x.w*x.w;
#pragma unroll
    for (int msk = 1; msk < 64; msk <<= 1) {
        sum += __shfl_xor(sum, msk);
        sq  += __shfl_xor(sq,  msk);
    }
    if ((tid & 63) == 0) { ssum[tid >> 6] = sum; ssq[tid >> 6] = sq; }
    __syncthreads();
    sum = ssum[0] + ssum[1] + ssum[2] + ssum[3];
    sq  = ssq[0]  + ssq[1]  + ssq[2]  + ssq[3];
    float mu  = sum * (1.f / 1024.f);
    float var = sq * (1.f / 1024.f) - mu * mu;
    float inv = rsqrtf(var + 1e-12f);
    float4 gv  = *(const float4*)&g[4 * tid];
    float4 bvv = *(const float4*)&be[4 * tid];
    float4 o;
    o.x = (x.x - mu) * inv * gv.x + bvv.x;
    o.y = (x.y - mu) * inv * gv.y + bvv.y;
    o.z = (x.z - mu) * inv * gv.z + bvv.z;
    o.w = (x.w - mu) * inv * gv.w + bvv.w;
    *(float4*)&out[(size_t)row * HIDD + 4 * tid] = o;
}

// ---------------------------------------------------------------------------
extern "C" void kernel_launch(void* const* d_in, const int* in_sizes, int n_in,
                              void* d_out, int out_size, void* d_ws, size_t ws_size,
                              hipStream_t stream)
{
    const float* hid  = (const float*)d_in[0];
    const float* mask = (const float*)d_in[1];
    const float* Wq   = (const float*)d_in[2];
    const float* bq   = (const float*)d_in[3];
    const float* Wk   = (const float*)d_in[4];
    const float* bk   = (const float*)d_in[5];
    const float* Wv   = (const float*)d_in[6];
    const float* bv   = (const float*)d_in[7];
    const float* de   = (const float*)d_in[8];
    const float* Wo   = (const float*)d_in[9];
    const float* bo   = (const float*)d_in[10];
    const float* lng  = (const float*)d_in[11];
    const float* lnb  = (const float*)d_in[12];
    float* out = (float*)d_out;

    unsigned short* hid_bf  = (unsigned short*)d_ws;         // 4M
    unsigned short* wqkv_bf = hid_bf  + 4194304;             // 3M (Wq|Wk|Wv)
    unsigned short* wo_bf   = wqkv_bf + 3145728;             // 1M (contig after wqkv)
    unsigned short* de_bf   = wo_bf   + 1048576;             // 131072 (2048 rows x 64)
    unsigned short* q_bf    = de_bf   + 131072;              // 4M  [bh][s][d]
    unsigned short* k_bf    = q_bf    + 4194304;             // 4M
    unsigned short* v_bf    = k_bf    + 4194304;             // 4M
    unsigned short* vt_bf   = v_bf    + 4194304;             // 4M  [bh][d][s]
    unsigned short* ctx_bf  = vt_bf   + 4194304;             // 4M  [b,s][h*64+d]
    float*          h_f     = (float*)q_bf;                  // 4M fp32 over dead q+k

    conv_f2b<<<2048, 256, 0, stream>>>(hid, hid_bf, 4194304);
    conv_w  <<<2048, 256, 0, stream>>>(Wq, Wk, Wv, Wo, wqkv_bf);
    conv_de <<<64,   256, 0, stream>>>(de, de_bf);

    gemm_bf16<<<dim3(32, 24), 256, 0, stream>>>(hid_bf, wqkv_bf, bq, bk, bv,
                                                nullptr, q_bf, k_bf, v_bf,
                                                nullptr, 1);
    vtrans<<<dim3(16, 64), 256, 0, stream>>>(v_bf, vt_bf);
    attn_mfma<<<dim3(16, 64), 256, 0, stream>>>(q_bf, k_bf, vt_bf, mask, de_bf,
                                                ctx_bf);
    gemm_bf16<<<dim3(32, 8), 256, 0, stream>>>(ctx_bf, wo_bf, bo, nullptr, nullptr,
                                               hid, nullptr, nullptr, nullptr,
                                               h_f, 0);
    ln_out<<<4096, 256, 0, stream>>>(h_f, lng, lnb, out);
}